// Round 4
// baseline (575.794 us; speedup 1.0000x reference)
//
#include <hip/hip_runtime.h>
#include <math.h>

// DhnLoss: NM=64, NQ=1024, NT=1024, f32.
// losses = [fp, fn, loc] (MISS_COST/ALPHA = 2.0/2.0 = 1.0), ha_mask (nm,nq,nt), amax_valid (nm,nt)
// d_out layout (float32): [0..3) losses | [3, 3+64M) ha_mask | [3+64M, +65536) amax_valid
//
// Fused single-read structure: KF reads A once, produces BOTH the row-softmax
// clutter sums (fp partials) and the column-softmax chunk partials (for fn/argmax).

#define NMc 64
#define NQc 1024
#define NTc 1024

static constexpr float KSC    = 144.269504089f;   // 100 * log2(e)
static constexpr float CLUT_P = 0.1f;             // clutter value in pre-scale space
static constexpr float CLUT_U = 14.4269504089f;   // 0.1 * 100 * log2(e)
static constexpr float L2E    = 1.44269504089f;   // log2(e)

static __device__ __forceinline__ float exp2fast(float x) {
  return __builtin_amdgcn_exp2f(x);
}

// ---------------- KF: fused row+col pass over a (qpc x 1024) tile of A. --------
// grid (nc, 64): blockIdx.x = q-chunk, blockIdx.y = m. 256 threads, 4 t-cols each.
__global__ __launch_bounds__(256) void k_fused(const float* __restrict__ A,
                                               const float* __restrict__ logits,
                                               float* __restrict__ fp_part,
                                               float* __restrict__ wsB,
                                               float* __restrict__ wsS,
                                               int* __restrict__ wsI,
                                               int qpc) {
  const int qc = blockIdx.x, m = blockIdx.y;
  const int q0 = qc * qpc;
  const int tid = threadIdx.x;
  const int wave = tid >> 6, lane = tid & 63;
  const int t0 = tid << 2;

  __shared__ float sigs[256];
  __shared__ float rowM[256][4];   // per-q, per-wave row max (u-space)
  __shared__ float rowS[256][4];   // per-q, per-wave row sumexp
  __shared__ float fpq[256];

  for (int i = tid; i < qpc; i += 256) {
    float x = logits[(m << 10) + q0 + i];
    sigs[i] = 1.f / (1.f + exp2fast(-L2E * x));
  }
  __syncthreads();

  const float* a = A + ((size_t)(m << 10) + q0) * NTc + t0;

  float M[4], S[4], bp[4];
  int bi[4];
#pragma unroll
  for (int c = 0; c < 4; ++c) { M[c] = -INFINITY; S[c] = 0.f; bp[c] = -INFINITY; bi[c] = q0; }

#pragma unroll 2
  for (int q = 0; q < qpc; ++q) {
    float4 v = *reinterpret_cast<const float4*>(a + ((size_t)q << 10));
    // ---- row pass (raw a, u-space) ----
    float ur[4] = {v.x * KSC, v.y * KSC, v.z * KSC, v.w * KSC};
    float m4 = fmaxf(fmaxf(ur[0], ur[1]), fmaxf(ur[2], ur[3]));
#pragma unroll
    for (int off = 32; off; off >>= 1) m4 = fmaxf(m4, __shfl_xor(m4, off, 64));
    float s4 = (exp2fast(ur[0] - m4) + exp2fast(ur[1] - m4)) +
               (exp2fast(ur[2] - m4) + exp2fast(ur[3] - m4));
#pragma unroll
    for (int off = 32; off; off >>= 1) s4 += __shfl_xor(s4, off, 64);
    if (lane == 0) { rowM[q][wave] = m4; rowS[q][wave] = s4; }
    // ---- col pass (fl(a*sig): reference ordering space) ----
    const float sg = sigs[q];
    float p[4] = {v.x * sg, v.y * sg, v.z * sg, v.w * sg};
#pragma unroll
    for (int c = 0; c < 4; ++c) {
      if (p[c] > bp[c]) { bp[c] = p[c]; bi[c] = q0 + q; }   // strict > == first-occurrence
      float u  = p[c] * KSC;
      float nM = fmaxf(M[c], u);
      S[c] = S[c] * exp2fast(M[c] - nM) + exp2fast(u - nM);
      M[c] = nM;
    }
  }

  // ---- col partials out ----
  const int idx = (qc << 16) + (m << 10) + t0;
#pragma unroll
  for (int c = 0; c < 4; ++c) {
    wsB[idx + c] = bp[c];
    wsS[idx + c] = S[c];
    wsI[idx + c] = bi[c];
  }

  // ---- fp: merge per-wave row partials, fold clutter, weight by sig ----
  __syncthreads();
  if (tid < qpc) {
    float Mr = rowM[tid][0], Sr = rowS[tid][0];
#pragma unroll
    for (int w = 1; w < 4; ++w) {
      float mo = rowM[tid][w], so = rowS[tid][w];
      float nm = fmaxf(Mr, mo);
      Sr = Sr * exp2fast(Mr - nm) + so * exp2fast(mo - nm);
      Mr = nm;
    }
    float nm = fmaxf(Mr, CLUT_U);
    float cl = exp2fast(CLUT_U - nm);
    fpq[tid] = cl / (Sr * exp2fast(Mr - nm) + cl) * sigs[tid];
  }
  __syncthreads();
  if (wave == 0) {
    float fp = 0.f;
    for (int k = lane; k < qpc; k += 64) fp += fpq[k];
#pragma unroll
    for (int off = 32; off; off >>= 1) fp += __shfl_xor(fp, off, 64);
    if (lane == 0) fp_part[blockIdx.y * gridDim.x + blockIdx.x] = fp;
  }
}

// ---------------- K3: merge chunks; fn, amax, amax_valid, loc gather. -----------
__global__ __launch_bounds__(256) void k_combine(const float* __restrict__ Dst,
                                                 const float* __restrict__ wsB,
                                                 const float* __restrict__ wsS,
                                                 const int* __restrict__ wsI,
                                                 int* __restrict__ amax,
                                                 float* __restrict__ amaxv,
                                                 float* __restrict__ fn_part,
                                                 float* __restrict__ loc_part,
                                                 int nc) {
  const int col = (blockIdx.x << 8) + threadIdx.x;  // m*1024 + t
  float M = -INFINITY, S = 0.f, gb = -INFINITY;
  int gi = 0;
  for (int qc = 0; qc < nc; ++qc) {                 // ascending q: first-occurrence wins
    const int idx = (qc << 16) + col;
    float bp = wsB[idx], Sc = wsS[idx];
    int Ic = wsI[idx];
    if (bp > gb) { gb = bp; gi = Ic; }
    float Mc = bp * KSC;                            // fl monotone: chunk max in u-space
    float nM = fmaxf(M, Mc);
    S = S * exp2fast(M - nM) + Sc * exp2fast(Mc - nM);
    M = nM;
  }
  amaxv[col] = (float)gi;                           // argmax over real queries only
  float nM = fmaxf(M, CLUT_U);
  float cl = exp2fast(CLUT_U - nM);
  float Sf = S * exp2fast(M - nM) + cl;
  float fn = cl / Sf;
  int am = (CLUT_P > gb) ? NQc : gi;                // clutter = index NQ (last); loses ties
  amax[col] = am;
  const int m = col >> 10, t = col & (NTc - 1);
  float locv = 0.f;
  if (am < NQc) locv = Dst[((size_t)(m << 10) + am) * NTc + t];
#pragma unroll
  for (int off = 32; off; off >>= 1) {
    fn   += __shfl_xor(fn, off, 64);
    locv += __shfl_xor(locv, off, 64);
  }
  __shared__ float rf[4], rl[4];
  const int wave = threadIdx.x >> 6, lane = threadIdx.x & 63;
  if (lane == 0) { rf[wave] = fn; rl[wave] = locv; }
  __syncthreads();
  if (threadIdx.x == 0) {
    fn_part[blockIdx.x]  = (rf[0] + rf[1]) + (rf[2] + rf[3]);
    loc_part[blockIdx.x] = (rl[0] + rl[1]) + (rl[2] + rl[3]);
  }
}

// ---------------- K4: materialize ha_mask (one block per (m,q) row). -----------
__global__ __launch_bounds__(256) void k_mask(const int* __restrict__ amax,
                                              float* __restrict__ ha) {
  const int row = blockIdx.x;                       // m*1024 + q
  const int m = row >> 10, q = row & 1023;
  const int4 am4 = reinterpret_cast<const int4*>(amax + (m << 10))[threadIdx.x];
  float4 o;
  o.x = (am4.x == q) ? 1.f : 0.f;
  o.y = (am4.y == q) ? 1.f : 0.f;
  o.z = (am4.z == q) ? 1.f : 0.f;
  o.w = (am4.w == q) ? 1.f : 0.f;
  reinterpret_cast<float4*>(ha + (size_t)row * NTc)[threadIdx.x] = o;
}

// ---------------- K5: final scalar reduce -> losses. ---------------------------
__global__ __launch_bounds__(256) void k_final(const float* __restrict__ fp_part,
                                               const float* __restrict__ fn_part,
                                               const float* __restrict__ loc_part,
                                               float* __restrict__ out,
                                               int npb) {
  float fp = 0.f;
  for (int i = threadIdx.x; i < npb; i += 256) fp += fp_part[i];
  float fn  = fn_part[threadIdx.x];
  float loc = loc_part[threadIdx.x];
#pragma unroll
  for (int off = 32; off; off >>= 1) {
    fp  += __shfl_xor(fp, off, 64);
    fn  += __shfl_xor(fn, off, 64);
    loc += __shfl_xor(loc, off, 64);
  }
  __shared__ float r[12];
  const int wave = threadIdx.x >> 6, lane = threadIdx.x & 63;
  if (lane == 0) { r[wave] = fp; r[4 + wave] = fn; r[8 + wave] = loc; }
  __syncthreads();
  if (threadIdx.x == 0) {
    // MISS_COST / ALPHA = 1.0
    out[0] = (r[0] + r[1]) + (r[2] + r[3]);
    out[1] = (r[4] + r[5]) + (r[6] + r[7]);
    out[2] = (r[8] + r[9]) + (r[10] + r[11]);
  }
}

extern "C" void kernel_launch(void* const* d_in, const int* in_sizes, int n_in,
                              void* d_out, int out_size, void* d_ws, size_t ws_size,
                              hipStream_t stream) {
  const float* A = (const float*)d_in[0];   // association (64,1024,1024)
  const float* D = (const float*)d_in[1];   // distance    (64,1024,1024)
  const float* L = (const float*)d_in[2];   // logits      (64,1024,1)
  float* out = (float*)d_out;

  // q-chunk count: prefer 16 (1024 blocks in KF -> 4/CU) if ws allows, else 8/4.
  const size_t colsz = (size_t)NMc * NTc;   // 65536
  auto need = [&](int nc) {
    return (size_t)(1024 * 4)               // fp_part
         + 3 * (size_t)nc * colsz * 4      // wsB, wsS, wsI
         + colsz * 4                        // amax
         + 2 * 256 * 4;                     // fn_part, loc_part
  };
  int nc = 16;
  if (need(16) > ws_size) nc = 8;
  if (need(8)  > ws_size) nc = 4;
  const int qpc = NQc / nc;                 // 64 / 128 / 256 (LDS sized for 256)

  char* ws = (char*)d_ws;
  float* fp_part  = (float*)ws;
  float* wsB      = (float*)(ws + 1024 * 4);
  float* wsS      = wsB + (size_t)nc * colsz;
  int*   wsI      = (int*)(wsS + (size_t)nc * colsz);
  int*   amax     = wsI + (size_t)nc * colsz;
  float* fn_part  = (float*)(amax + colsz);
  float* loc_part = fn_part + 256;

  float* ha    = out + 3;
  float* amaxv = out + 3 + (size_t)NMc * NQc * NTc;

  hipLaunchKernelGGL(k_fused,   dim3(nc, 64), dim3(256), 0, stream,
                     A, L, fp_part, wsB, wsS, wsI, qpc);
  hipLaunchKernelGGL(k_combine, dim3(256),    dim3(256), 0, stream, D, wsB, wsS, wsI,
                     amax, amaxv, fn_part, loc_part, nc);
  hipLaunchKernelGGL(k_mask,    dim3(65536),  dim3(256), 0, stream, amax, ha);
  hipLaunchKernelGGL(k_final,   dim3(1),      dim3(256), 0, stream,
                     fp_part, fn_part, loc_part, out, nc * 64);
}